// Round 6
// baseline (532.372 us; speedup 1.0000x reference)
//
#include <hip/hip_runtime.h>
#include <hip/hip_bf16.h>
#include <cstdint>
#include <cstddef>

#define NGENE 100000
#define NDIS  20000
#define FDIM  128
#define HIDD  128
#define OUTF  64
#define EGG   400000
#define EGD   100000
#define EDG   100000
#define ETOT  (EGG + EGD + EDG)
#define NSLOT (NGENE + NDIS + NGENE)   // g2g dst [0,NG) | g2d dst [NG,NG+ND) | d2g dst [NG+ND,...)
#define NSRC  (2 * NGENE + NDIS)       // src rows: gene t0 -> 2n, gene t1 -> 2n+1, dis t2 -> 2NG+d
#define SLOPE 0.2f

typedef __attribute__((ext_vector_type(8))) short short8;
typedef __attribute__((ext_vector_type(4))) float f32x4;

static __device__ __forceinline__ float leaky(float x) { return x > 0.f ? x : SLOPE * x; }

static __device__ __forceinline__ ushort f2b(float x) {  // fp32 -> bf16 RNE
    uint u = __float_as_uint(x);
    return (ushort)((u + 0x7fffu + ((u >> 16) & 1u)) >> 16);
}
static __device__ __forceinline__ float b2f(uint s) { return __uint_as_float(s << 16); }
static __device__ __forceinline__ uint pack2(float lo, float hi) {
    return (uint)f2b(lo) | ((uint)f2b(hi) << 16);
}

// ---------------------------------------------------------------- converts
__global__ __launch_bounds__(256) void conv_f32_bf16(const float* __restrict__ in,
                                                     ushort* __restrict__ out, int n4)
{
    int i = blockIdx.x * 256 + threadIdx.x;
    if (i >= n4) return;
    float4 v = ((const float4*)in)[i];
    ushort4 o; o.x = f2b(v.x); o.y = f2b(v.y); o.z = f2b(v.z); o.w = f2b(v.w);
    ((ushort4*)out)[i] = o;
}

// all weight transposes in one launch: W [k x C] fp32 -> Wt [C x k(128)] bf16
__global__ __launch_bounds__(256) void conv_wt_all(const float* __restrict__ Ws1, const float* __restrict__ Ws2,
                                                   const float* __restrict__ Wg,  const float* __restrict__ Wd,
                                                   ushort* __restrict__ wt1, ushort* __restrict__ wt2,
                                                   ushort* __restrict__ wtg, ushort* __restrict__ wtd)
{
    int i = blockIdx.x * 256 + threadIdx.x;          // total 114688
    if (i < 49152) {
        int t = i >> 14, r = i & 16383; int c = r >> 7, k = r & 127;
        wt1[i] = f2b(Ws1[(size_t)t * 16384 + k * 128 + c]);
    } else if (i < 98304) {
        int j = i - 49152;
        int t = j >> 14, r = j & 16383; int c = r >> 7, k = r & 127;
        wt2[j] = f2b(Ws2[(size_t)t * 16384 + k * 128 + c]);
    } else if (i < 106496) {
        int j = i - 98304; int c = j >> 7, k = j & 127;
        wtg[j] = f2b(Wg[k * 64 + c]);
    } else if (i < 114688) {
        int j = i - 106496; int c = j >> 7, k = j & 127;
        wtd[j] = f2b(Wd[k * 64 + c]);
    }
}

// ---------------------------------------------------------------- attention vectors: av[mat][f] = sum_h W[t][f][h]*a[t][h]
__global__ __launch_bounds__(64) void compute_av(const float* __restrict__ Ws1, const float* __restrict__ Wd1,
                                                 const float* __restrict__ as1, const float* __restrict__ ad1,
                                                 const float* __restrict__ Ws2, const float* __restrict__ Wd2,
                                                 const float* __restrict__ as2, const float* __restrict__ ad2,
                                                 float* __restrict__ av)
{
    int b = blockIdx.x;              // 0..1535
    int mat = b >> 7, f = b & 127;   // mats: [layer][vs0,vs1,vs2,vd0,vd1,vd2]
    int layer = mat / 6, idx = mat % 6;
    int t = (idx < 3) ? idx : idx - 3;
    const float* W; const float* a;
    if (layer == 0) { W = (idx < 3) ? Ws1 : Wd1; a = (idx < 3) ? as1 : ad1; }
    else           { W = (idx < 3) ? Ws2 : Wd2; a = (idx < 3) ? as2 : ad2; }
    const float* Wrow = W + ((size_t)t * 128 + f) * 128;
    const float* avec = a + t * 128;
    int lane = threadIdx.x;
    float2 w  = ((const float2*)Wrow)[lane];
    float2 aa = ((const float2*)avec)[lane];
    float d = w.x * aa.x + w.y * aa.y;
    for (int off = 32; off; off >>= 1) d += __shfl_down(d, off);
    if (lane == 0) av[mat * 128 + f] = d;
}

// ---------------------------------------------------------------- MFMA GEMM + fused per-node dots
// [N,128]bf16 @ Wt[NCOL,128]bf16. B-fragments read DIRECTLY from global (W is
// L2-resident and shared by all blocks; staging it in LDS capped occupancy at
// 2 blocks/CU and caused 1.7M bank conflicts in r5). LDS holds only the X tile.
template<int NCOL, int NDOT, bool OUT_BF16>
__global__ __launch_bounds__(256) void gemm_mfma(const ushort* __restrict__ X,
                                                 const ushort* __restrict__ Wt,
                                                 const float* __restrict__ bias,
                                                 void* __restrict__ H, int N,
                                                 const float* __restrict__ av, int4 vidx,
                                                 float* __restrict__ oes,
                                                 float* __restrict__ oda,
                                                 float* __restrict__ odb)
{
    __shared__ ushort xs[64 * 128];
    const int tid = threadIdx.x;
    const int r0  = blockIdx.x * 64;

    for (int ci = tid; ci < 1024; ci += 256) {             // stage X tile (swizzled)
        int r = ci >> 4; int bc = (ci & 15) << 4;
        int4 v = make_int4(0, 0, 0, 0);
        if (r0 + r < N) v = *(const int4*)((const char*)X + (size_t)(r0 + r) * 256 + bc);
        *(int4*)((char*)xs + r * 256 + (bc ^ ((r & 7) << 4))) = v;
    }
    __syncthreads();

    const int w = tid >> 6, l = tid & 63;
    const int lr = l & 15, lk = l >> 4;
    f32x4 acc[NCOL / 16];
    #pragma unroll
    for (int i = 0; i < NCOL / 16; ++i) acc[i] = f32x4{0.f, 0.f, 0.f, 0.f};

    const short8* Wt8 = (const short8*)Wt;                 // row stride = 16 (16B units)
    #pragma unroll
    for (int ks = 0; ks < 4; ++ks) {
        int ar = w * 16 + lr;
        short8 a = *(const short8*)((const char*)xs + ar * 256 + ((ks * 64 + lk * 16) ^ ((ar & 7) << 4)));
        #pragma unroll
        for (int nt = 0; nt < NCOL / 16; ++nt) {
            int bcoln = nt * 16 + lr;
            short8 b = Wt8[bcoln * 16 + ks * 4 + lk];      // global/L2 direct
            acc[nt] = __builtin_amdgcn_mfma_f32_16x16x32_bf16(a, b, acc[nt], 0, 0, 0);
        }
    }

    #pragma unroll
    for (int nt = 0; nt < NCOL / 16; ++nt) {
        int col = nt * 16 + lr;
        float bv = OUT_BF16 ? 0.f : bias[col];
        #pragma unroll
        for (int q = 0; q < 4; ++q) {
            int gr = r0 + w * 16 + lk * 4 + q;             // C/D: col=lane&15, row=(lane>>4)*4+reg
            if (gr < N) {
                if (OUT_BF16) ((ushort*)H)[(size_t)gr * NCOL + col] = f2b(acc[nt][q]);
                else          ((float*)H)[(size_t)gr * NCOL + col] = acc[nt][q] + bv;
            }
        }
    }

    if (NDOT > 0) {                                        // fused per-node dots from LDS x
        int row = tid >> 2;        // 0..63
        int kq  = tid & 3;         // 32-value k quarter
        int gr  = r0 + row;
        float xv[32];
        #pragma unroll
        for (int j = 0; j < 4; ++j) {
            int bc = kq * 64 + j * 16;
            uint4 u = *(const uint4*)((const char*)xs + row * 256 + (bc ^ ((row & 7) << 4)));
            xv[j*8+0] = b2f(u.x & 0xffffu); xv[j*8+1] = b2f(u.x >> 16);
            xv[j*8+2] = b2f(u.y & 0xffffu); xv[j*8+3] = b2f(u.y >> 16);
            xv[j*8+4] = b2f(u.z & 0xffffu); xv[j*8+5] = b2f(u.z >> 16);
            xv[j*8+6] = b2f(u.w & 0xffffu); xv[j*8+7] = b2f(u.w >> 16);
        }
        int vi[4] = { vidx.x, vidx.y, vidx.z, vidx.w };
        float dots[NDOT > 0 ? NDOT : 1];
        #pragma unroll
        for (int v = 0; v < NDOT; ++v) {
            const float* a = av + vi[v] * 128 + kq * 32;
            float d = 0.f;
            #pragma unroll
            for (int k = 0; k < 32; ++k) d += xv[k] * a[k];
            d += __shfl_xor(d, 1);
            d += __shfl_xor(d, 2);
            dots[v] = d;
        }
        if (kq == 0 && gr < N) {
            if (NDOT == 4) {
                *(float2*)(oes + 2 * gr) = make_float2(dots[0], dots[1]);
                oda[gr] = dots[2];
                odb[gr] = dots[3];
            } else if (NDOT == 2) {
                oes[gr] = dots[0];
                oda[gr] = dots[1];
            }
        }
    }
}

// ---------------------------------------------------------------- CSR build
__global__ void hist_edges(const int* __restrict__ gg_d, const int* __restrict__ gd_d,
                           const int* __restrict__ dg_d, int* __restrict__ counts)
{
    int i = blockIdx.x * blockDim.x + threadIdx.x;
    if (i >= ETOT) return;
    int slot;
    if (i < EGG) slot = gg_d[i];
    else if (i < EGG + EGD) slot = NGENE + gd_d[i - EGG];
    else slot = NGENE + NDIS + dg_d[i - EGG - EGD];
    atomicAdd(&counts[slot], 1);
}

__global__ __launch_bounds__(256) void scan_blocks(const int* __restrict__ counts, int* __restrict__ rowptr,
                                                   int* __restrict__ partials, int n)
{
    __shared__ int sdata[256];
    int base = blockIdx.x * 2048;
    int tid  = threadIdx.x;
    int local[8]; int s = 0;
    #pragma unroll
    for (int j = 0; j < 8; ++j) {
        int idx = base + tid * 8 + j;
        int v = (idx < n) ? counts[idx] : 0;
        local[j] = s; s += v;
    }
    sdata[tid] = s;
    __syncthreads();
    for (int off = 1; off < 256; off <<= 1) {
        int v = 0;
        if (tid >= off) v = sdata[tid - off];
        __syncthreads();
        if (tid >= off) sdata[tid] += v;
        __syncthreads();
    }
    int texcl = (tid ? sdata[tid - 1] : 0);
    #pragma unroll
    for (int j = 0; j < 8; ++j) {
        int idx = base + tid * 8 + j;
        if (idx < n) rowptr[idx] = local[j] + texcl;
    }
    if (tid == 255) partials[blockIdx.x] = sdata[255];
}

__global__ __launch_bounds__(256) void scan_partials(int* __restrict__ partials, int nb)
{
    __shared__ int sdata[256];
    int tid = threadIdx.x;
    sdata[tid] = (tid < nb) ? partials[tid] : 0;
    __syncthreads();
    for (int off = 1; off < 256; off <<= 1) {
        int v = 0;
        if (tid >= off) v = sdata[tid - off];
        __syncthreads();
        if (tid >= off) sdata[tid] += v;
        __syncthreads();
    }
    partials[tid] = (tid ? sdata[tid - 1] : 0);
}

__global__ void scan_add(int* __restrict__ rowptr, const int* __restrict__ partials, int n)
{
    int i = blockIdx.x * blockDim.x + threadIdx.x;
    if (i < n) rowptr[i] += partials[i >> 11];
    if (i == 0) rowptr[n] = ETOT;
}

// scatter: single 4B store per edge (unified source index encodes projection row)
__global__ void scatter_edges(const int* __restrict__ gg_s, const int* __restrict__ gg_d,
                              const int* __restrict__ gd_s, const int* __restrict__ gd_d,
                              const int* __restrict__ dg_s, const int* __restrict__ dg_d,
                              const int* __restrict__ rowptr, int* __restrict__ cursor,
                              int* __restrict__ colu)
{
    int i = blockIdx.x * blockDim.x + threadIdx.x;
    if (i >= ETOT) return;
    int slot, srcu;
    if (i < EGG) { slot = gg_d[i]; srcu = 2 * gg_s[i]; }
    else if (i < EGG + EGD) { int j = i - EGG; slot = NGENE + gd_d[j]; srcu = 2 * gd_s[j] + 1; }
    else { int j = i - EGG - EGD; slot = NGENE + NDIS + dg_d[j]; srcu = 2 * NGENE + dg_s[j]; }
    int pos = atomicAdd(&cursor[slot], 1);
    colu[rowptr[slot] + pos] = srcu;
}

// ---------------------------------------------------------------- aggregate: inline softmax, 16 lanes/node
__device__ __forceinline__ void seg_go(int slot, const int* __restrict__ rowptr,
                                       const int* __restrict__ colu, const float* __restrict__ su,
                                       const float* __restrict__ edu, const uint4* __restrict__ hsu,
                                       int gl, float acc[8])
{
    int s = rowptr[slot], e = rowptr[slot + 1];
    if (e <= s) return;
    float edv = edu[slot];
    float sx[8];
    #pragma unroll
    for (int j = 0; j < 8; ++j) sx[j] = 0.f;
    float den = 0.f;
    int c = colu[s]; float sc = su[c];
    uint4 h = hsu[(size_t)c * 16 + gl];
    for (int i = s + 1; i < e; ++i) {
        int c1 = colu[i]; float sc1 = su[c1];
        uint4 h1 = hsu[(size_t)c1 * 16 + gl];          // in flight while consuming h
        float el = sc + edv; el = el > 0.f ? el : SLOPE * el;
        float p = __expf(fminf(el, 80.f));
        den += p;
        sx[0] += p * b2f(h.x & 0xffffu); sx[1] += p * b2f(h.x >> 16);
        sx[2] += p * b2f(h.y & 0xffffu); sx[3] += p * b2f(h.y >> 16);
        sx[4] += p * b2f(h.z & 0xffffu); sx[5] += p * b2f(h.z >> 16);
        sx[6] += p * b2f(h.w & 0xffffu); sx[7] += p * b2f(h.w >> 16);
        sc = sc1; h = h1;
    }
    float el = sc + edv; el = el > 0.f ? el : SLOPE * el;
    float p = __expf(fminf(el, 80.f));
    den += p;
    sx[0] += p * b2f(h.x & 0xffffu); sx[1] += p * b2f(h.x >> 16);
    sx[2] += p * b2f(h.y & 0xffffu); sx[3] += p * b2f(h.y >> 16);
    sx[4] += p * b2f(h.z & 0xffffu); sx[5] += p * b2f(h.z >> 16);
    sx[6] += p * b2f(h.w & 0xffffu); sx[7] += p * b2f(h.w >> 16);
    float inv = 1.0f / den;
    #pragma unroll
    for (int j = 0; j < 8; ++j) acc[j] += sx[j] * inv;
}

template<bool TWO>
__global__ __launch_bounds__(256) void agg_seg(const int* __restrict__ rowptr, const int* __restrict__ colu,
                                              const float* __restrict__ su, const float* __restrict__ edu,
                                              const uint4* __restrict__ hsu,
                                              int slotA0, int slotB0,
                                              const float* __restrict__ biasA, const float* __restrict__ biasB,
                                              uint4* __restrict__ out, int N)
{
    int g  = blockIdx.x * 16 + (threadIdx.x >> 4);
    int gl = threadIdx.x & 15;
    if (g >= N) return;
    float acc[8];
    #pragma unroll
    for (int j = 0; j < 8; ++j) acc[j] = 0.f;
    seg_go(slotA0 + g, rowptr, colu, su, edu, hsu, gl, acc);
    if (TWO) seg_go(slotB0 + g, rowptr, colu, su, edu, hsu, gl, acc);

    float4 bA0 = ((const float4*)biasA)[gl * 2];
    float4 bA1 = ((const float4*)biasA)[gl * 2 + 1];
    float b0 = bA0.x, b1 = bA0.y, b2 = bA0.z, b3 = bA0.w;
    float b4 = bA1.x, b5 = bA1.y, b6 = bA1.z, b7 = bA1.w;
    if (TWO) {
        float4 bB0 = ((const float4*)biasB)[gl * 2];
        float4 bB1 = ((const float4*)biasB)[gl * 2 + 1];
        b0 += bB0.x; b1 += bB0.y; b2 += bB0.z; b3 += bB0.w;
        b4 += bB1.x; b5 += bB1.y; b6 += bB1.z; b7 += bB1.w;
    }
    uint4 o;
    o.x = pack2(fmaxf(acc[0] + b0, 0.f), fmaxf(acc[1] + b1, 0.f));
    o.y = pack2(fmaxf(acc[2] + b2, 0.f), fmaxf(acc[3] + b3, 0.f));
    o.z = pack2(fmaxf(acc[4] + b4, 0.f), fmaxf(acc[5] + b5, 0.f));
    o.w = pack2(fmaxf(acc[6] + b6, 0.f), fmaxf(acc[7] + b7, 0.f));
    out[(size_t)g * 16 + gl] = o;
}

// ---------------------------------------------------------------- launch
extern "C" void kernel_launch(void* const* d_in, const int* in_sizes, int n_in,
                              void* d_out, int out_size, void* d_ws, size_t ws_size,
                              hipStream_t stream)
{
    const float* xg  = (const float*)d_in[0];
    const float* xd  = (const float*)d_in[1];
    const float* Ws1 = (const float*)d_in[2];
    const float* Wd1 = (const float*)d_in[3];
    const float* as1 = (const float*)d_in[4];
    const float* ad1 = (const float*)d_in[5];
    const float* b1  = (const float*)d_in[6];
    const float* Ws2 = (const float*)d_in[7];
    const float* Wd2 = (const float*)d_in[8];
    const float* as2 = (const float*)d_in[9];
    const float* ad2 = (const float*)d_in[10];
    const float* b2  = (const float*)d_in[11];
    const float* Wg  = (const float*)d_in[12];
    const float* bg  = (const float*)d_in[13];
    const float* Wdh = (const float*)d_in[14];
    const float* bd  = (const float*)d_in[15];
    const int* gg_s = (const int*)d_in[16];
    const int* gg_d = (const int*)d_in[17];
    const int* gd_s = (const int*)d_in[18];
    const int* gd_d = (const int*)d_in[19];
    const int* dg_s = (const int*)d_in[20];
    const int* dg_d = (const int*)d_in[21];
    float* out = (float*)d_out;

    size_t p = 0;
    char* ws = (char*)d_ws;
    auto alloc_f = [&](size_t n) { p = (p + 255) & ~(size_t)255; float* r = (float*)(ws + p);  p += n * sizeof(float);  return r; };
    auto alloc_i = [&](size_t n) { p = (p + 255) & ~(size_t)255; int* r = (int*)(ws + p);      p += n * sizeof(int);    return r; };
    auto alloc_u = [&](size_t n) { p = (p + 255) & ~(size_t)255; ushort* r = (ushort*)(ws + p); p += n * sizeof(ushort); return r; };

    ushort* xgb  = alloc_u((size_t)NGENE * FDIM);
    ushort* xdb  = alloc_u((size_t)NDIS  * FDIM);
    ushort* hsu  = alloc_u((size_t)NSRC * HIDD);   // rows: gene t0=2n, t1=2n+1 | dis t2 = 2NG+d
    ushort* h1gb = alloc_u((size_t)NGENE * HIDD);
    ushort* h1db = alloc_u((size_t)NDIS  * HIDD);
    ushort* wt1  = alloc_u(3 * 128 * 128);
    ushort* wt2  = alloc_u(3 * 128 * 128);
    ushort* wtg  = alloc_u(64 * 128);
    ushort* wtd  = alloc_u(64 * 128);
    float* av   = alloc_f(12 * 128);
    float* esu  = alloc_f(NSRC);        // matches srcu indexing
    float* edu  = alloc_f(NSLOT);       // matches slot indexing
    int* counts   = alloc_i(NSLOT);
    int* rowptr   = alloc_i(NSLOT + 1);
    int* partials = alloc_i(256);
    int* colu     = alloc_i(ETOT);
    (void)ws_size; (void)in_sizes; (void)n_in; (void)out_size;

    const int SCAN_BLOCKS = (NSLOT + 2047) / 2048;   // 108

    ushort* hs_dis = hsu + (size_t)2 * NGENE * HIDD;
    float* es_dis = esu + 2 * NGENE;
    float* ed0 = edu;                    // gene dst of g2g
    float* ed1 = edu + NGENE;            // dis dst of g2d
    float* ed2 = edu + NGENE + NDIS;     // gene dst of d2g

    // ---- CSR build (shared by both layers)
    hipMemsetAsync(counts, 0, (size_t)NSLOT * sizeof(int), stream);
    hist_edges<<<(ETOT + 255) / 256, 256, 0, stream>>>(gg_d, gd_d, dg_d, counts);
    scan_blocks<<<SCAN_BLOCKS, 256, 0, stream>>>(counts, rowptr, partials, NSLOT);
    scan_partials<<<1, 256, 0, stream>>>(partials, SCAN_BLOCKS);
    scan_add<<<(NSLOT + 255) / 256, 256, 0, stream>>>(rowptr, partials, NSLOT);
    hipMemsetAsync(counts, 0, (size_t)NSLOT * sizeof(int), stream);
    scatter_edges<<<(ETOT + 255) / 256, 256, 0, stream>>>(gg_s, gg_d, gd_s, gd_d, dg_s, dg_d,
                                                          rowptr, counts, colu);

    // ---- bf16 conversions + attention vectors
    conv_f32_bf16<<<(NGENE * FDIM / 4 + 255) / 256, 256, 0, stream>>>(xg, xgb, NGENE * FDIM / 4);
    conv_f32_bf16<<<(NDIS  * FDIM / 4 + 255) / 256, 256, 0, stream>>>(xd, xdb, NDIS * FDIM / 4);
    conv_wt_all<<<448, 256, 0, stream>>>(Ws1, Ws2, Wg, Wdh, wt1, wt2, wtg, wtd);
    compute_av<<<1536, 64, 0, stream>>>(Ws1, Wd1, as1, ad1, Ws2, Wd2, as2, ad2, av);

    const int GB_G = (NGENE + 63) / 64, GB_D = (NDIS + 63) / 64;
    const int AB_G = (NGENE + 15) / 16, AB_D = (NDIS + 15) / 16;

    // ---- layer 1: fused dual projection + dots (gene), projection + dots (dis)
    gemm_mfma<256, 4, true><<<GB_G, 256, 0, stream>>>(xgb, wt1, nullptr, hsu, NGENE,
        av, make_int4(0, 1, 3, 5), esu, ed0, ed2);
    gemm_mfma<128, 2, true><<<GB_D, 256, 0, stream>>>(xdb, wt1 + 2 * 128 * 128, nullptr, hs_dis, NDIS,
        av, make_int4(2, 4, 0, 0), es_dis, ed1, nullptr);
    agg_seg<true><<<AB_G, 256, 0, stream>>>(rowptr, colu, esu, edu, (const uint4*)hsu,
        0, NGENE + NDIS, b1 + 0 * 128, b1 + 2 * 128, (uint4*)h1gb, NGENE);
    agg_seg<false><<<AB_D, 256, 0, stream>>>(rowptr, colu, esu, edu, (const uint4*)hsu,
        NGENE, 0, b1 + 1 * 128, nullptr, (uint4*)h1db, NDIS);

    // ---- layer 2
    gemm_mfma<256, 4, true><<<GB_G, 256, 0, stream>>>(h1gb, wt2, nullptr, hsu, NGENE,
        av, make_int4(6, 7, 9, 11), esu, ed0, ed2);
    gemm_mfma<128, 2, true><<<GB_D, 256, 0, stream>>>(h1db, wt2 + 2 * 128 * 128, nullptr, hs_dis, NDIS,
        av, make_int4(8, 10, 0, 0), es_dis, ed1, nullptr);
    agg_seg<true><<<AB_G, 256, 0, stream>>>(rowptr, colu, esu, edu, (const uint4*)hsu,
        0, NGENE + NDIS, b2 + 0 * 128, b2 + 2 * 128, (uint4*)h1gb, NGENE);
    agg_seg<false><<<AB_D, 256, 0, stream>>>(rowptr, colu, esu, edu, (const uint4*)hsu,
        NGENE, 0, b2 + 1 * 128, nullptr, (uint4*)h1db, NDIS);

    // ---- output heads (bf16 MFMA, fp32 out + bias, gene first)
    gemm_mfma<64, 0, false><<<GB_G, 256, 0, stream>>>(h1gb, wtg, bg, out, NGENE,
        av, make_int4(0, 0, 0, 0), nullptr, nullptr, nullptr);
    gemm_mfma<64, 0, false><<<GB_D, 256, 0, stream>>>(h1db, wtd, bd, out + (size_t)NGENE * OUTF, NDIS,
        av, make_int4(0, 0, 0, 0), nullptr, nullptr, nullptr);
}

// Round 7
// 447.548 us; speedup vs baseline: 1.1895x; 1.1895x over previous
//
#include <hip/hip_runtime.h>
#include <hip/hip_bf16.h>
#include <cstdint>
#include <cstddef>

#define NGENE 100000
#define NDIS  20000
#define FDIM  128
#define HIDD  128
#define OUTF  64
#define EGG   400000
#define EGD   100000
#define EDG   100000
#define ETOT  (EGG + EGD + EDG)
#define NSLOT (NGENE + NDIS + NGENE)   // g2g dst [0,NG) | g2d dst [NG,NG+ND) | d2g dst [NG+ND,...)
#define NSRC  (2 * NGENE + NDIS)       // src rows: gene t0 -> 2n, gene t1 -> 2n+1, dis t2 -> 2NG+d
#define SLOPE 0.2f

typedef __attribute__((ext_vector_type(8))) short short8;
typedef __attribute__((ext_vector_type(4))) float f32x4;

static __device__ __forceinline__ float leaky(float x) { return x > 0.f ? x : SLOPE * x; }

static __device__ __forceinline__ ushort f2b(float x) {  // fp32 -> bf16 RNE
    uint u = __float_as_uint(x);
    return (ushort)((u + 0x7fffu + ((u >> 16) & 1u)) >> 16);
}
static __device__ __forceinline__ float b2f(uint s) { return __uint_as_float(s << 16); }
static __device__ __forceinline__ uint pack2(float lo, float hi) {
    return (uint)f2b(lo) | ((uint)f2b(hi) << 16);
}

// ---------------------------------------------------------------- converts
__global__ __launch_bounds__(256) void conv_f32_bf16(const float* __restrict__ in,
                                                     ushort* __restrict__ out, int n4)
{
    int i = blockIdx.x * 256 + threadIdx.x;
    if (i >= n4) return;
    float4 v = ((const float4*)in)[i];
    ushort4 o; o.x = f2b(v.x); o.y = f2b(v.y); o.z = f2b(v.z); o.w = f2b(v.w);
    ((ushort4*)out)[i] = o;
}

// all weight transposes in one launch: W [k x C] fp32 -> Wt [C x k(128)] bf16
__global__ __launch_bounds__(256) void conv_wt_all(const float* __restrict__ Ws1, const float* __restrict__ Ws2,
                                                   const float* __restrict__ Wg,  const float* __restrict__ Wd,
                                                   ushort* __restrict__ wt1, ushort* __restrict__ wt2,
                                                   ushort* __restrict__ wtg, ushort* __restrict__ wtd)
{
    int i = blockIdx.x * 256 + threadIdx.x;          // total 114688
    if (i < 49152) {
        int t = i >> 14, r = i & 16383; int c = r >> 7, k = r & 127;
        wt1[i] = f2b(Ws1[(size_t)t * 16384 + k * 128 + c]);
    } else if (i < 98304) {
        int j = i - 49152;
        int t = j >> 14, r = j & 16383; int c = r >> 7, k = r & 127;
        wt2[j] = f2b(Ws2[(size_t)t * 16384 + k * 128 + c]);
    } else if (i < 106496) {
        int j = i - 98304; int c = j >> 7, k = j & 127;
        wtg[j] = f2b(Wg[k * 64 + c]);
    } else if (i < 114688) {
        int j = i - 106496; int c = j >> 7, k = j & 127;
        wtd[j] = f2b(Wd[k * 64 + c]);
    }
}

// ---------------------------------------------------------------- attention vectors: av[mat][f] = sum_h W[t][f][h]*a[t][h]
__global__ __launch_bounds__(64) void compute_av(const float* __restrict__ Ws1, const float* __restrict__ Wd1,
                                                 const float* __restrict__ as1, const float* __restrict__ ad1,
                                                 const float* __restrict__ Ws2, const float* __restrict__ Wd2,
                                                 const float* __restrict__ as2, const float* __restrict__ ad2,
                                                 float* __restrict__ av)
{
    int b = blockIdx.x;              // 0..1535
    int mat = b >> 7, f = b & 127;   // mats: [layer][vs0,vs1,vs2,vd0,vd1,vd2]
    int layer = mat / 6, idx = mat % 6;
    int t = (idx < 3) ? idx : idx - 3;
    const float* W; const float* a;
    if (layer == 0) { W = (idx < 3) ? Ws1 : Wd1; a = (idx < 3) ? as1 : ad1; }
    else           { W = (idx < 3) ? Ws2 : Wd2; a = (idx < 3) ? as2 : ad2; }
    const float* Wrow = W + ((size_t)t * 128 + f) * 128;
    const float* avec = a + t * 128;
    int lane = threadIdx.x;
    float2 w  = ((const float2*)Wrow)[lane];
    float2 aa = ((const float2*)avec)[lane];
    float d = w.x * aa.x + w.y * aa.y;
    for (int off = 32; off; off >>= 1) d += __shfl_down(d, off);
    if (lane == 0) av[mat * 128 + f] = d;
}

// ---------------------------------------------------------------- MFMA GEMM + fused per-node dots
// [N,128]bf16 @ Wt[NCOL,128]bf16. Wave w owns cols [w*NCOL/4, +NCOL/4): its whole
// B-slice is preloaded into REGISTERS (NT*4 short8 = loop-invariant; r6 showed
// per-MFMA global B reads are latency-bound; r5 showed LDS-staged W caps occupancy).
// LDS holds only the 16KB X tile (swizzled), reused by the fused dots epilogue.
template<int NCOL, int NDOT, bool OUT_BF16>
__global__ __launch_bounds__(256) void gemm_mfma(const ushort* __restrict__ X,
                                                 const ushort* __restrict__ Wt,
                                                 const float* __restrict__ bias,
                                                 void* __restrict__ H, int N,
                                                 const float* __restrict__ av, int4 vidx,
                                                 float* __restrict__ oes,
                                                 float* __restrict__ oda,
                                                 float* __restrict__ odb)
{
    constexpr int NT  = NCOL / 64;        // 16-col tiles per wave
    constexpr int CPW = NCOL / 4;         // cols per wave
    __shared__ ushort xs[64 * 128];
    const int tid = threadIdx.x;
    const int r0  = blockIdx.x * 64;
    const int w = tid >> 6, l = tid & 63;
    const int lr = l & 15, lk = l >> 4;

    // preload B-slice into registers (L2-hot, once per block)
    short8 bfrag[NT][4];
    const short8* Wt8 = (const short8*)Wt;                 // col stride = 16 short8
    #pragma unroll
    for (int nt = 0; nt < NT; ++nt)
        #pragma unroll
        for (int ks = 0; ks < 4; ++ks)
            bfrag[nt][ks] = Wt8[(w * CPW + nt * 16 + lr) * 16 + ks * 4 + lk];

    for (int ci = tid; ci < 1024; ci += 256) {             // stage X tile (swizzled)
        int r = ci >> 4; int bc = (ci & 15) << 4;
        int4 v = make_int4(0, 0, 0, 0);
        if (r0 + r < N) v = *(const int4*)((const char*)X + (size_t)(r0 + r) * 256 + bc);
        *(int4*)((char*)xs + r * 256 + (bc ^ ((r & 7) << 4))) = v;
    }
    __syncthreads();

    f32x4 acc[4][NT];
    #pragma unroll
    for (int rc = 0; rc < 4; ++rc)
        #pragma unroll
        for (int nt = 0; nt < NT; ++nt) acc[rc][nt] = f32x4{0.f, 0.f, 0.f, 0.f};

    #pragma unroll
    for (int rc = 0; rc < 4; ++rc) {
        int ar = rc * 16 + lr;
        #pragma unroll
        for (int ks = 0; ks < 4; ++ks) {
            short8 a = *(const short8*)((const char*)xs + ar * 256 + ((ks * 64 + lk * 16) ^ ((ar & 7) << 4)));
            #pragma unroll
            for (int nt = 0; nt < NT; ++nt)
                acc[rc][nt] = __builtin_amdgcn_mfma_f32_16x16x32_bf16(a, bfrag[nt][ks], acc[rc][nt], 0, 0, 0);
        }
    }

    #pragma unroll
    for (int rc = 0; rc < 4; ++rc) {
        #pragma unroll
        for (int nt = 0; nt < NT; ++nt) {
            int col = w * CPW + nt * 16 + lr;
            float bv = OUT_BF16 ? 0.f : bias[col];
            #pragma unroll
            for (int q = 0; q < 4; ++q) {
                int gr = r0 + rc * 16 + lk * 4 + q;        // C/D: col=lane&15, row=(lane>>4)*4+reg
                if (gr < N) {
                    if (OUT_BF16) ((ushort*)H)[(size_t)gr * NCOL + col] = f2b(acc[rc][nt][q]);
                    else          ((float*)H)[(size_t)gr * NCOL + col] = acc[rc][nt][q] + bv;
                }
            }
        }
    }

    if (NDOT > 0) {                                        // fused per-node dots from LDS x
        int row = tid >> 2;        // 0..63
        int kq  = tid & 3;         // 32-value k quarter
        int gr  = r0 + row;
        float xv[32];
        #pragma unroll
        for (int j = 0; j < 4; ++j) {
            int bc = kq * 64 + j * 16;
            uint4 u = *(const uint4*)((const char*)xs + row * 256 + (bc ^ ((row & 7) << 4)));
            xv[j*8+0] = b2f(u.x & 0xffffu); xv[j*8+1] = b2f(u.x >> 16);
            xv[j*8+2] = b2f(u.y & 0xffffu); xv[j*8+3] = b2f(u.y >> 16);
            xv[j*8+4] = b2f(u.z & 0xffffu); xv[j*8+5] = b2f(u.z >> 16);
            xv[j*8+6] = b2f(u.w & 0xffffu); xv[j*8+7] = b2f(u.w >> 16);
        }
        int vi[4] = { vidx.x, vidx.y, vidx.z, vidx.w };
        float dots[NDOT > 0 ? NDOT : 1];
        #pragma unroll
        for (int v = 0; v < NDOT; ++v) {
            const float* a = av + vi[v] * 128 + kq * 32;
            float d = 0.f;
            #pragma unroll
            for (int k = 0; k < 32; ++k) d += xv[k] * a[k];
            d += __shfl_xor(d, 1);
            d += __shfl_xor(d, 2);
            dots[v] = d;
        }
        if (kq == 0 && gr < N) {
            if (NDOT == 4) {
                *(float2*)(oes + 2 * gr) = make_float2(dots[0], dots[1]);
                oda[gr] = dots[2];
                odb[gr] = dots[3];
            } else if (NDOT == 2) {
                oes[gr] = dots[0];
                oda[gr] = dots[1];
            }
        }
    }
}

// ---------------------------------------------------------------- CSR build
__global__ void hist_edges(const int* __restrict__ gg_d, const int* __restrict__ gd_d,
                           const int* __restrict__ dg_d, int* __restrict__ counts)
{
    int i = blockIdx.x * blockDim.x + threadIdx.x;
    if (i >= ETOT) return;
    int slot;
    if (i < EGG) slot = gg_d[i];
    else if (i < EGG + EGD) slot = NGENE + gd_d[i - EGG];
    else slot = NGENE + NDIS + dg_d[i - EGG - EGD];
    atomicAdd(&counts[slot], 1);
}

__global__ __launch_bounds__(256) void scan_blocks(const int* __restrict__ counts, int* __restrict__ rowptr,
                                                   int* __restrict__ partials, int n)
{
    __shared__ int sdata[256];
    int base = blockIdx.x * 2048;
    int tid  = threadIdx.x;
    int local[8]; int s = 0;
    #pragma unroll
    for (int j = 0; j < 8; ++j) {
        int idx = base + tid * 8 + j;
        int v = (idx < n) ? counts[idx] : 0;
        local[j] = s; s += v;
    }
    sdata[tid] = s;
    __syncthreads();
    for (int off = 1; off < 256; off <<= 1) {
        int v = 0;
        if (tid >= off) v = sdata[tid - off];
        __syncthreads();
        if (tid >= off) sdata[tid] += v;
        __syncthreads();
    }
    int texcl = (tid ? sdata[tid - 1] : 0);
    #pragma unroll
    for (int j = 0; j < 8; ++j) {
        int idx = base + tid * 8 + j;
        if (idx < n) rowptr[idx] = local[j] + texcl;
    }
    if (tid == 255) partials[blockIdx.x] = sdata[255];
}

__global__ __launch_bounds__(256) void scan_partials(int* __restrict__ partials, int nb)
{
    __shared__ int sdata[256];
    int tid = threadIdx.x;
    sdata[tid] = (tid < nb) ? partials[tid] : 0;
    __syncthreads();
    for (int off = 1; off < 256; off <<= 1) {
        int v = 0;
        if (tid >= off) v = sdata[tid - off];
        __syncthreads();
        if (tid >= off) sdata[tid] += v;
        __syncthreads();
    }
    partials[tid] = (tid ? sdata[tid - 1] : 0);
}

// finalize rowptr AND initialize cursor (saves a memset + rowptr gather in scatter)
__global__ void scan_add(int* __restrict__ rowptr, const int* __restrict__ partials, int n,
                         int* __restrict__ cursor)
{
    int i = blockIdx.x * blockDim.x + threadIdx.x;
    if (i < n) {
        int v = rowptr[i] + partials[i >> 11];
        rowptr[i] = v;
        cursor[i] = v;
    }
    if (i == 0) rowptr[n] = ETOT;
}

// scatter: single 4B store per edge (unified source index encodes projection row)
__global__ void scatter_edges(const int* __restrict__ gg_s, const int* __restrict__ gg_d,
                              const int* __restrict__ gd_s, const int* __restrict__ gd_d,
                              const int* __restrict__ dg_s, const int* __restrict__ dg_d,
                              int* __restrict__ cursor, int* __restrict__ colu)
{
    int i = blockIdx.x * blockDim.x + threadIdx.x;
    if (i >= ETOT) return;
    int slot, srcu;
    if (i < EGG) { slot = gg_d[i]; srcu = 2 * gg_s[i]; }
    else if (i < EGG + EGD) { int j = i - EGG; slot = NGENE + gd_d[j]; srcu = 2 * gd_s[j] + 1; }
    else { int j = i - EGG - EGD; slot = NGENE + NDIS + dg_d[j]; srcu = 2 * NGENE + dg_s[j]; }
    int pos = atomicAdd(&cursor[slot], 1);
    colu[pos] = srcu;
}

// ---------------------------------------------------------------- aggregate: inline softmax, 16 lanes/node
__device__ __forceinline__ void seg_go(int slot, const int* __restrict__ rowptr,
                                       const int* __restrict__ colu, const float* __restrict__ su,
                                       const float* __restrict__ edu, const uint4* __restrict__ hsu,
                                       int gl, float acc[8])
{
    int s = rowptr[slot], e = rowptr[slot + 1];
    if (e <= s) return;
    float edv = edu[slot];
    float sx[8];
    #pragma unroll
    for (int j = 0; j < 8; ++j) sx[j] = 0.f;
    float den = 0.f;
    int c = colu[s]; float sc = su[c];
    uint4 h = hsu[(size_t)c * 16 + gl];
    for (int i = s + 1; i < e; ++i) {
        int c1 = colu[i]; float sc1 = su[c1];
        uint4 h1 = hsu[(size_t)c1 * 16 + gl];          // in flight while consuming h
        float el = sc + edv; el = el > 0.f ? el : SLOPE * el;
        float p = __expf(fminf(el, 80.f));
        den += p;
        sx[0] += p * b2f(h.x & 0xffffu); sx[1] += p * b2f(h.x >> 16);
        sx[2] += p * b2f(h.y & 0xffffu); sx[3] += p * b2f(h.y >> 16);
        sx[4] += p * b2f(h.z & 0xffffu); sx[5] += p * b2f(h.z >> 16);
        sx[6] += p * b2f(h.w & 0xffffu); sx[7] += p * b2f(h.w >> 16);
        sc = sc1; h = h1;
    }
    float el = sc + edv; el = el > 0.f ? el : SLOPE * el;
    float p = __expf(fminf(el, 80.f));
    den += p;
    sx[0] += p * b2f(h.x & 0xffffu); sx[1] += p * b2f(h.x >> 16);
    sx[2] += p * b2f(h.y & 0xffffu); sx[3] += p * b2f(h.y >> 16);
    sx[4] += p * b2f(h.z & 0xffffu); sx[5] += p * b2f(h.z >> 16);
    sx[6] += p * b2f(h.w & 0xffffu); sx[7] += p * b2f(h.w >> 16);
    float inv = 1.0f / den;
    #pragma unroll
    for (int j = 0; j < 8; ++j) acc[j] += sx[j] * inv;
}

template<bool TWO>
__global__ __launch_bounds__(256) void agg_seg(const int* __restrict__ rowptr, const int* __restrict__ colu,
                                              const float* __restrict__ su, const float* __restrict__ edu,
                                              const uint4* __restrict__ hsu,
                                              int slotA0, int slotB0,
                                              const float* __restrict__ biasA, const float* __restrict__ biasB,
                                              uint4* __restrict__ out, int N)
{
    int g  = blockIdx.x * 16 + (threadIdx.x >> 4);
    int gl = threadIdx.x & 15;
    if (g >= N) return;
    float acc[8];
    #pragma unroll
    for (int j = 0; j < 8; ++j) acc[j] = 0.f;
    seg_go(slotA0 + g, rowptr, colu, su, edu, hsu, gl, acc);
    if (TWO) seg_go(slotB0 + g, rowptr, colu, su, edu, hsu, gl, acc);

    float4 bA0 = ((const float4*)biasA)[gl * 2];
    float4 bA1 = ((const float4*)biasA)[gl * 2 + 1];
    float b0 = bA0.x, b1 = bA0.y, b2 = bA0.z, b3 = bA0.w;
    float b4 = bA1.x, b5 = bA1.y, b6 = bA1.z, b7 = bA1.w;
    if (TWO) {
        float4 bB0 = ((const float4*)biasB)[gl * 2];
        float4 bB1 = ((const float4*)biasB)[gl * 2 + 1];
        b0 += bB0.x; b1 += bB0.y; b2 += bB0.z; b3 += bB0.w;
        b4 += bB1.x; b5 += bB1.y; b6 += bB1.z; b7 += bB1.w;
    }
    uint4 o;
    o.x = pack2(fmaxf(acc[0] + b0, 0.f), fmaxf(acc[1] + b1, 0.f));
    o.y = pack2(fmaxf(acc[2] + b2, 0.f), fmaxf(acc[3] + b3, 0.f));
    o.z = pack2(fmaxf(acc[4] + b4, 0.f), fmaxf(acc[5] + b5, 0.f));
    o.w = pack2(fmaxf(acc[6] + b6, 0.f), fmaxf(acc[7] + b7, 0.f));
    out[(size_t)g * 16 + gl] = o;
}

// ---------------------------------------------------------------- launch
extern "C" void kernel_launch(void* const* d_in, const int* in_sizes, int n_in,
                              void* d_out, int out_size, void* d_ws, size_t ws_size,
                              hipStream_t stream)
{
    const float* xg  = (const float*)d_in[0];
    const float* xd  = (const float*)d_in[1];
    const float* Ws1 = (const float*)d_in[2];
    const float* Wd1 = (const float*)d_in[3];
    const float* as1 = (const float*)d_in[4];
    const float* ad1 = (const float*)d_in[5];
    const float* b1  = (const float*)d_in[6];
    const float* Ws2 = (const float*)d_in[7];
    const float* Wd2 = (const float*)d_in[8];
    const float* as2 = (const float*)d_in[9];
    const float* ad2 = (const float*)d_in[10];
    const float* b2  = (const float*)d_in[11];
    const float* Wg  = (const float*)d_in[12];
    const float* bg  = (const float*)d_in[13];
    const float* Wdh = (const float*)d_in[14];
    const float* bd  = (const float*)d_in[15];
    const int* gg_s = (const int*)d_in[16];
    const int* gg_d = (const int*)d_in[17];
    const int* gd_s = (const int*)d_in[18];
    const int* gd_d = (const int*)d_in[19];
    const int* dg_s = (const int*)d_in[20];
    const int* dg_d = (const int*)d_in[21];
    float* out = (float*)d_out;

    size_t p = 0;
    char* ws = (char*)d_ws;
    auto alloc_f = [&](size_t n) { p = (p + 255) & ~(size_t)255; float* r = (float*)(ws + p);  p += n * sizeof(float);  return r; };
    auto alloc_i = [&](size_t n) { p = (p + 255) & ~(size_t)255; int* r = (int*)(ws + p);      p += n * sizeof(int);    return r; };
    auto alloc_u = [&](size_t n) { p = (p + 255) & ~(size_t)255; ushort* r = (ushort*)(ws + p); p += n * sizeof(ushort); return r; };

    ushort* xgb  = alloc_u((size_t)NGENE * FDIM);
    ushort* xdb  = alloc_u((size_t)NDIS  * FDIM);
    ushort* hsu  = alloc_u((size_t)NSRC * HIDD);   // rows: gene t0=2n, t1=2n+1 | dis t2 = 2NG+d
    ushort* h1gb = alloc_u((size_t)NGENE * HIDD);
    ushort* h1db = alloc_u((size_t)NDIS  * HIDD);
    ushort* wt1  = alloc_u(3 * 128 * 128);
    ushort* wt2  = alloc_u(3 * 128 * 128);
    ushort* wtg  = alloc_u(64 * 128);
    ushort* wtd  = alloc_u(64 * 128);
    float* av   = alloc_f(12 * 128);
    float* esu  = alloc_f(NSRC);        // matches srcu indexing
    float* edu  = alloc_f(NSLOT);       // matches slot indexing
    int* counts   = alloc_i(NSLOT);
    int* rowptr   = alloc_i(NSLOT + 1);
    int* partials = alloc_i(256);
    int* colu     = alloc_i(ETOT);
    (void)ws_size; (void)in_sizes; (void)n_in; (void)out_size;

    const int SCAN_BLOCKS = (NSLOT + 2047) / 2048;   // 108

    ushort* hs_dis = hsu + (size_t)2 * NGENE * HIDD;
    float* es_dis = esu + 2 * NGENE;
    float* ed0 = edu;                    // gene dst of g2g
    float* ed1 = edu + NGENE;            // dis dst of g2d
    float* ed2 = edu + NGENE + NDIS;     // gene dst of d2g

    // ---- CSR build (shared by both layers); counts doubles as cursor
    hipMemsetAsync(counts, 0, (size_t)NSLOT * sizeof(int), stream);
    hist_edges<<<(ETOT + 255) / 256, 256, 0, stream>>>(gg_d, gd_d, dg_d, counts);
    scan_blocks<<<SCAN_BLOCKS, 256, 0, stream>>>(counts, rowptr, partials, NSLOT);
    scan_partials<<<1, 256, 0, stream>>>(partials, SCAN_BLOCKS);
    scan_add<<<(NSLOT + 255) / 256, 256, 0, stream>>>(rowptr, partials, NSLOT, counts);
    scatter_edges<<<(ETOT + 255) / 256, 256, 0, stream>>>(gg_s, gg_d, gd_s, gd_d, dg_s, dg_d,
                                                          counts, colu);

    // ---- bf16 conversions + attention vectors
    conv_f32_bf16<<<(NGENE * FDIM / 4 + 255) / 256, 256, 0, stream>>>(xg, xgb, NGENE * FDIM / 4);
    conv_f32_bf16<<<(NDIS  * FDIM / 4 + 255) / 256, 256, 0, stream>>>(xd, xdb, NDIS * FDIM / 4);
    conv_wt_all<<<448, 256, 0, stream>>>(Ws1, Ws2, Wg, Wdh, wt1, wt2, wtg, wtd);
    compute_av<<<1536, 64, 0, stream>>>(Ws1, Wd1, as1, ad1, Ws2, Wd2, as2, ad2, av);

    const int GB_G = (NGENE + 63) / 64, GB_D = (NDIS + 63) / 64;
    const int AB_G = (NGENE + 15) / 16, AB_D = (NDIS + 15) / 16;

    // ---- layer 1: fused dual projection + dots (gene), projection + dots (dis)
    gemm_mfma<256, 4, true><<<GB_G, 256, 0, stream>>>(xgb, wt1, nullptr, hsu, NGENE,
        av, make_int4(0, 1, 3, 5), esu, ed0, ed2);
    gemm_mfma<128, 2, true><<<GB_D, 256, 0, stream>>>(xdb, wt1 + 2 * 128 * 128, nullptr, hs_dis, NDIS,
        av, make_int4(2, 4, 0, 0), es_dis, ed1, nullptr);
    agg_seg<true><<<AB_G, 256, 0, stream>>>(rowptr, colu, esu, edu, (const uint4*)hsu,
        0, NGENE + NDIS, b1 + 0 * 128, b1 + 2 * 128, (uint4*)h1gb, NGENE);
    agg_seg<false><<<AB_D, 256, 0, stream>>>(rowptr, colu, esu, edu, (const uint4*)hsu,
        NGENE, 0, b1 + 1 * 128, nullptr, (uint4*)h1db, NDIS);

    // ---- layer 2
    gemm_mfma<256, 4, true><<<GB_G, 256, 0, stream>>>(h1gb, wt2, nullptr, hsu, NGENE,
        av, make_int4(6, 7, 9, 11), esu, ed0, ed2);
    gemm_mfma<128, 2, true><<<GB_D, 256, 0, stream>>>(h1db, wt2 + 2 * 128 * 128, nullptr, hs_dis, NDIS,
        av, make_int4(8, 10, 0, 0), es_dis, ed1, nullptr);
    agg_seg<true><<<AB_G, 256, 0, stream>>>(rowptr, colu, esu, edu, (const uint4*)hsu,
        0, NGENE + NDIS, b2 + 0 * 128, b2 + 2 * 128, (uint4*)h1gb, NGENE);
    agg_seg<false><<<AB_D, 256, 0, stream>>>(rowptr, colu, esu, edu, (const uint4*)hsu,
        NGENE, 0, b2 + 1 * 128, nullptr, (uint4*)h1db, NDIS);

    // ---- output heads (bf16 MFMA, fp32 out + bias, gene first)
    gemm_mfma<64, 0, false><<<GB_G, 256, 0, stream>>>(h1gb, wtg, bg, out, NGENE,
        av, make_int4(0, 0, 0, 0), nullptr, nullptr, nullptr);
    gemm_mfma<64, 0, false><<<GB_D, 256, 0, stream>>>(h1db, wtd, bd, out + (size_t)NGENE * OUTF, NDIS,
        av, make_int4(0, 0, 0, 0), nullptr, nullptr, nullptr);
}

// Round 8
// 404.452 us; speedup vs baseline: 1.3163x; 1.1066x over previous
//
#include <hip/hip_runtime.h>
#include <hip/hip_bf16.h>
#include <cstdint>
#include <cstddef>

#define NGENE 100000
#define NDIS  20000
#define FDIM  128
#define HIDD  128
#define OUTF  64
#define EGG   400000
#define EGD   100000
#define EDG   100000
#define ETOT  (EGG + EGD + EDG)
#define NSLOT (NGENE + NDIS + NGENE)   // g2g dst [0,NG) | g2d dst [NG,NG+ND) | d2g dst [NG+ND,...)
#define NSRC  (2 * NGENE + NDIS)       // src rows: gene t0 -> 2n, gene t1 -> 2n+1, dis t2 -> 2NG+d
#define SLOPE 0.2f

typedef __attribute__((ext_vector_type(8))) short short8;
typedef __attribute__((ext_vector_type(4))) float f32x4;

static __device__ __forceinline__ float leaky(float x) { return x > 0.f ? x : SLOPE * x; }

static __device__ __forceinline__ ushort f2b(float x) {  // fp32 -> bf16 RNE
    uint u = __float_as_uint(x);
    return (ushort)((u + 0x7fffu + ((u >> 16) & 1u)) >> 16);
}
static __device__ __forceinline__ float b2f(uint s) { return __uint_as_float(s << 16); }
static __device__ __forceinline__ uint pack2(float lo, float hi) {
    return (uint)f2b(lo) | ((uint)f2b(hi) << 16);
}

// ---------------------------------------------------------------- converts
__global__ __launch_bounds__(256) void conv_f32_bf16(const float* __restrict__ in,
                                                     ushort* __restrict__ out, int n4)
{
    int i = blockIdx.x * 256 + threadIdx.x;
    if (i >= n4) return;
    float4 v = ((const float4*)in)[i];
    ushort4 o; o.x = f2b(v.x); o.y = f2b(v.y); o.z = f2b(v.z); o.w = f2b(v.w);
    ((ushort4*)out)[i] = o;
}

// all weight transposes in one launch: W [k x C] fp32 -> Wt [C x k(128)] bf16
__global__ __launch_bounds__(256) void conv_wt_all(const float* __restrict__ Ws1, const float* __restrict__ Ws2,
                                                   const float* __restrict__ Wg,  const float* __restrict__ Wd,
                                                   ushort* __restrict__ wt1, ushort* __restrict__ wt2,
                                                   ushort* __restrict__ wtg, ushort* __restrict__ wtd)
{
    int i = blockIdx.x * 256 + threadIdx.x;          // total 114688
    if (i < 49152) {
        int t = i >> 14, r = i & 16383; int c = r >> 7, k = r & 127;
        wt1[i] = f2b(Ws1[(size_t)t * 16384 + k * 128 + c]);
    } else if (i < 98304) {
        int j = i - 49152;
        int t = j >> 14, r = j & 16383; int c = r >> 7, k = r & 127;
        wt2[j] = f2b(Ws2[(size_t)t * 16384 + k * 128 + c]);
    } else if (i < 106496) {
        int j = i - 98304; int c = j >> 7, k = j & 127;
        wtg[j] = f2b(Wg[k * 64 + c]);
    } else if (i < 114688) {
        int j = i - 106496; int c = j >> 7, k = j & 127;
        wtd[j] = f2b(Wd[k * 64 + c]);
    }
}

// ---------------------------------------------------------------- attention vectors: av[mat][f] = sum_h W[t][f][h]*a[t][h]
__global__ __launch_bounds__(64) void compute_av(const float* __restrict__ Ws1, const float* __restrict__ Wd1,
                                                 const float* __restrict__ as1, const float* __restrict__ ad1,
                                                 const float* __restrict__ Ws2, const float* __restrict__ Wd2,
                                                 const float* __restrict__ as2, const float* __restrict__ ad2,
                                                 float* __restrict__ av)
{
    int b = blockIdx.x;              // 0..1535
    int mat = b >> 7, f = b & 127;   // mats: [layer][vs0,vs1,vs2,vd0,vd1,vd2]
    int layer = mat / 6, idx = mat % 6;
    int t = (idx < 3) ? idx : idx - 3;
    const float* W; const float* a;
    if (layer == 0) { W = (idx < 3) ? Ws1 : Wd1; a = (idx < 3) ? as1 : ad1; }
    else           { W = (idx < 3) ? Ws2 : Wd2; a = (idx < 3) ? as2 : ad2; }
    const float* Wrow = W + ((size_t)t * 128 + f) * 128;
    const float* avec = a + t * 128;
    int lane = threadIdx.x;
    float2 w  = ((const float2*)Wrow)[lane];
    float2 aa = ((const float2*)avec)[lane];
    float d = w.x * aa.x + w.y * aa.y;
    for (int off = 32; off; off >>= 1) d += __shfl_down(d, off);
    if (lane == 0) av[mat * 128 + f] = d;
}

// ---------------------------------------------------------------- MFMA GEMM + fused per-node dots
// [N,128]bf16 @ Wt[NCOL,128]bf16. WAVES waves/block; wave w owns a 16*NT-col slice.
// r7 lesson: acc AGPRs count against the unified file — 4-wave/64-col slices hit
// ~172 regs -> 2 waves/SIMD, latency-bound. 8-wave/32-col slices halve bfrag+acc
// (~96 regs) -> 4 waves/SIMD. B-slice preloaded to registers (L2-hot), X in LDS.
template<int NCOL, int WAVES, int NDOT, bool OUT_BF16>
__global__ __launch_bounds__(WAVES * 64) void gemm_mfma(const ushort* __restrict__ X,
                                                        const ushort* __restrict__ Wt,
                                                        const float* __restrict__ bias,
                                                        void* __restrict__ H, int N,
                                                        const float* __restrict__ av, int4 vidx,
                                                        float* __restrict__ oes,
                                                        float* __restrict__ oda,
                                                        float* __restrict__ odb)
{
    constexpr int NT  = NCOL / (16 * WAVES);  // 16-col tiles per wave
    constexpr int CPW = 16 * NT;              // cols per wave
    __shared__ ushort xs[64 * 128];
    const int tid = threadIdx.x;
    const int r0  = blockIdx.x * 64;
    const int w = tid >> 6, l = tid & 63;
    const int lr = l & 15, lk = l >> 4;

    // preload B-slice into registers (L2-hot, once per block)
    short8 bfrag[NT][4];
    const short8* Wt8 = (const short8*)Wt;                 // col stride = 16 short8
    #pragma unroll
    for (int nt = 0; nt < NT; ++nt)
        #pragma unroll
        for (int ks = 0; ks < 4; ++ks)
            bfrag[nt][ks] = Wt8[(w * CPW + nt * 16 + lr) * 16 + ks * 4 + lk];

    for (int ci = tid; ci < 1024; ci += WAVES * 64) {      // stage X tile (swizzled)
        int r = ci >> 4; int bc = (ci & 15) << 4;
        int4 v = make_int4(0, 0, 0, 0);
        if (r0 + r < N) v = *(const int4*)((const char*)X + (size_t)(r0 + r) * 256 + bc);
        *(int4*)((char*)xs + r * 256 + (bc ^ ((r & 7) << 4))) = v;
    }
    __syncthreads();

    f32x4 acc[4][NT];
    #pragma unroll
    for (int rc = 0; rc < 4; ++rc)
        #pragma unroll
        for (int nt = 0; nt < NT; ++nt) acc[rc][nt] = f32x4{0.f, 0.f, 0.f, 0.f};

    #pragma unroll
    for (int rc = 0; rc < 4; ++rc) {
        int ar = rc * 16 + lr;
        #pragma unroll
        for (int ks = 0; ks < 4; ++ks) {
            short8 a = *(const short8*)((const char*)xs + ar * 256 + ((ks * 64 + lk * 16) ^ ((ar & 7) << 4)));
            #pragma unroll
            for (int nt = 0; nt < NT; ++nt)
                acc[rc][nt] = __builtin_amdgcn_mfma_f32_16x16x32_bf16(a, bfrag[nt][ks], acc[rc][nt], 0, 0, 0);
        }
    }

    #pragma unroll
    for (int rc = 0; rc < 4; ++rc) {
        #pragma unroll
        for (int nt = 0; nt < NT; ++nt) {
            int col = w * CPW + nt * 16 + lr;
            float bv = OUT_BF16 ? 0.f : bias[col];
            #pragma unroll
            for (int q = 0; q < 4; ++q) {
                int gr = r0 + rc * 16 + lk * 4 + q;        // C/D: col=lane&15, row=(lane>>4)*4+reg
                if (gr < N) {
                    if (OUT_BF16) ((ushort*)H)[(size_t)gr * NCOL + col] = f2b(acc[rc][nt][q]);
                    else          ((float*)H)[(size_t)gr * NCOL + col] = acc[rc][nt][q] + bv;
                }
            }
        }
    }

    if (NDOT > 0) {                                        // fused per-node dots from LDS x
        constexpr int TPR = WAVES;          // threads per row
        constexpr int KCH = 128 / TPR;      // k-elements per thread
        int row = tid / TPR;                // 0..63
        int kq  = tid % TPR;
        int gr  = r0 + row;
        float xv[KCH];
        #pragma unroll
        for (int j = 0; j < KCH / 8; ++j) {
            int bc = kq * (KCH * 2) + j * 16;
            uint4 u = *(const uint4*)((const char*)xs + row * 256 + (bc ^ ((row & 7) << 4)));
            xv[j*8+0] = b2f(u.x & 0xffffu); xv[j*8+1] = b2f(u.x >> 16);
            xv[j*8+2] = b2f(u.y & 0xffffu); xv[j*8+3] = b2f(u.y >> 16);
            xv[j*8+4] = b2f(u.z & 0xffffu); xv[j*8+5] = b2f(u.z >> 16);
            xv[j*8+6] = b2f(u.w & 0xffffu); xv[j*8+7] = b2f(u.w >> 16);
        }
        int vi[4] = { vidx.x, vidx.y, vidx.z, vidx.w };
        float dots[NDOT > 0 ? NDOT : 1];
        #pragma unroll
        for (int v = 0; v < NDOT; ++v) {
            const float* a = av + vi[v] * 128 + kq * KCH;
            float d = 0.f;
            #pragma unroll
            for (int k = 0; k < KCH; ++k) d += xv[k] * a[k];
            #pragma unroll
            for (int off = 1; off < TPR; off <<= 1) d += __shfl_xor(d, off);
            dots[v] = d;
        }
        if (kq == 0 && gr < N) {
            if (NDOT == 4) {
                *(float2*)(oes + 2 * gr) = make_float2(dots[0], dots[1]);
                oda[gr] = dots[2];
                odb[gr] = dots[3];
            } else if (NDOT == 2) {
                oes[gr] = dots[0];
                oda[gr] = dots[1];
            }
        }
    }
}

// ---------------------------------------------------------------- CSR build
__global__ void hist_edges(const int* __restrict__ gg_d, const int* __restrict__ gd_d,
                           const int* __restrict__ dg_d, int* __restrict__ counts)
{
    int i = blockIdx.x * blockDim.x + threadIdx.x;
    if (i >= ETOT) return;
    int slot;
    if (i < EGG) slot = gg_d[i];
    else if (i < EGG + EGD) slot = NGENE + gd_d[i - EGG];
    else slot = NGENE + NDIS + dg_d[i - EGG - EGD];
    atomicAdd(&counts[slot], 1);
}

__global__ __launch_bounds__(256) void scan_blocks(const int* __restrict__ counts, int* __restrict__ rowptr,
                                                   int* __restrict__ partials, int n)
{
    __shared__ int sdata[256];
    int base = blockIdx.x * 2048;
    int tid  = threadIdx.x;
    int local[8]; int s = 0;
    #pragma unroll
    for (int j = 0; j < 8; ++j) {
        int idx = base + tid * 8 + j;
        int v = (idx < n) ? counts[idx] : 0;
        local[j] = s; s += v;
    }
    sdata[tid] = s;
    __syncthreads();
    for (int off = 1; off < 256; off <<= 1) {
        int v = 0;
        if (tid >= off) v = sdata[tid - off];
        __syncthreads();
        if (tid >= off) sdata[tid] += v;
        __syncthreads();
    }
    int texcl = (tid ? sdata[tid - 1] : 0);
    #pragma unroll
    for (int j = 0; j < 8; ++j) {
        int idx = base + tid * 8 + j;
        if (idx < n) rowptr[idx] = local[j] + texcl;
    }
    if (tid == 255) partials[blockIdx.x] = sdata[255];
}

__global__ __launch_bounds__(256) void scan_partials(int* __restrict__ partials, int nb)
{
    __shared__ int sdata[256];
    int tid = threadIdx.x;
    sdata[tid] = (tid < nb) ? partials[tid] : 0;
    __syncthreads();
    for (int off = 1; off < 256; off <<= 1) {
        int v = 0;
        if (tid >= off) v = sdata[tid - off];
        __syncthreads();
        if (tid >= off) sdata[tid] += v;
        __syncthreads();
    }
    partials[tid] = (tid ? sdata[tid - 1] : 0);
}

// finalize rowptr AND initialize cursor (saves a memset + rowptr gather in scatter)
__global__ void scan_add(int* __restrict__ rowptr, const int* __restrict__ partials, int n,
                         int* __restrict__ cursor)
{
    int i = blockIdx.x * blockDim.x + threadIdx.x;
    if (i < n) {
        int v = rowptr[i] + partials[i >> 11];
        rowptr[i] = v;
        cursor[i] = v;
    }
    if (i == 0) rowptr[n] = ETOT;
}

// scatter: single 4B store per edge (unified source index encodes projection row)
__global__ void scatter_edges(const int* __restrict__ gg_s, const int* __restrict__ gg_d,
                              const int* __restrict__ gd_s, const int* __restrict__ gd_d,
                              const int* __restrict__ dg_s, const int* __restrict__ dg_d,
                              int* __restrict__ cursor, int* __restrict__ colu)
{
    int i = blockIdx.x * blockDim.x + threadIdx.x;
    if (i >= ETOT) return;
    int slot, srcu;
    if (i < EGG) { slot = gg_d[i]; srcu = 2 * gg_s[i]; }
    else if (i < EGG + EGD) { int j = i - EGG; slot = NGENE + gd_d[j]; srcu = 2 * gd_s[j] + 1; }
    else { int j = i - EGG - EGD; slot = NGENE + NDIS + dg_d[j]; srcu = 2 * NGENE + dg_s[j]; }
    int pos = atomicAdd(&cursor[slot], 1);
    colu[pos] = srcu;
}

// ---------------------------------------------------------------- aggregate: inline softmax, 16 lanes/node
__device__ __forceinline__ void seg_go(int slot, const int* __restrict__ rowptr,
                                       const int* __restrict__ colu, const float* __restrict__ su,
                                       const float* __restrict__ edu, const uint4* __restrict__ hsu,
                                       int gl, float acc[8])
{
    int s = rowptr[slot], e = rowptr[slot + 1];
    if (e <= s) return;
    float edv = edu[slot];
    float sx[8];
    #pragma unroll
    for (int j = 0; j < 8; ++j) sx[j] = 0.f;
    float den = 0.f;
    int c = colu[s]; float sc = su[c];
    uint4 h = hsu[(size_t)c * 16 + gl];
    for (int i = s + 1; i < e; ++i) {
        int c1 = colu[i]; float sc1 = su[c1];
        uint4 h1 = hsu[(size_t)c1 * 16 + gl];          // in flight while consuming h
        float el = sc + edv; el = el > 0.f ? el : SLOPE * el;
        float p = __expf(fminf(el, 80.f));
        den += p;
        sx[0] += p * b2f(h.x & 0xffffu); sx[1] += p * b2f(h.x >> 16);
        sx[2] += p * b2f(h.y & 0xffffu); sx[3] += p * b2f(h.y >> 16);
        sx[4] += p * b2f(h.z & 0xffffu); sx[5] += p * b2f(h.z >> 16);
        sx[6] += p * b2f(h.w & 0xffffu); sx[7] += p * b2f(h.w >> 16);
        sc = sc1; h = h1;
    }
    float el = sc + edv; el = el > 0.f ? el : SLOPE * el;
    float p = __expf(fminf(el, 80.f));
    den += p;
    sx[0] += p * b2f(h.x & 0xffffu); sx[1] += p * b2f(h.x >> 16);
    sx[2] += p * b2f(h.y & 0xffffu); sx[3] += p * b2f(h.y >> 16);
    sx[4] += p * b2f(h.z & 0xffffu); sx[5] += p * b2f(h.z >> 16);
    sx[6] += p * b2f(h.w & 0xffffu); sx[7] += p * b2f(h.w >> 16);
    float inv = 1.0f / den;
    #pragma unroll
    for (int j = 0; j < 8; ++j) acc[j] += sx[j] * inv;
}

template<bool TWO>
__global__ __launch_bounds__(256) void agg_seg(const int* __restrict__ rowptr, const int* __restrict__ colu,
                                              const float* __restrict__ su, const float* __restrict__ edu,
                                              const uint4* __restrict__ hsu,
                                              int slotA0, int slotB0,
                                              const float* __restrict__ biasA, const float* __restrict__ biasB,
                                              uint4* __restrict__ out, int N)
{
    int g  = blockIdx.x * 16 + (threadIdx.x >> 4);
    int gl = threadIdx.x & 15;
    if (g >= N) return;
    float acc[8];
    #pragma unroll
    for (int j = 0; j < 8; ++j) acc[j] = 0.f;
    seg_go(slotA0 + g, rowptr, colu, su, edu, hsu, gl, acc);
    if (TWO) seg_go(slotB0 + g, rowptr, colu, su, edu, hsu, gl, acc);

    float4 bA0 = ((const float4*)biasA)[gl * 2];
    float4 bA1 = ((const float4*)biasA)[gl * 2 + 1];
    float b0 = bA0.x, b1 = bA0.y, b2 = bA0.z, b3 = bA0.w;
    float b4 = bA1.x, b5 = bA1.y, b6 = bA1.z, b7 = bA1.w;
    if (TWO) {
        float4 bB0 = ((const float4*)biasB)[gl * 2];
        float4 bB1 = ((const float4*)biasB)[gl * 2 + 1];
        b0 += bB0.x; b1 += bB0.y; b2 += bB0.z; b3 += bB0.w;
        b4 += bB1.x; b5 += bB1.y; b6 += bB1.z; b7 += bB1.w;
    }
    uint4 o;
    o.x = pack2(fmaxf(acc[0] + b0, 0.f), fmaxf(acc[1] + b1, 0.f));
    o.y = pack2(fmaxf(acc[2] + b2, 0.f), fmaxf(acc[3] + b3, 0.f));
    o.z = pack2(fmaxf(acc[4] + b4, 0.f), fmaxf(acc[5] + b5, 0.f));
    o.w = pack2(fmaxf(acc[6] + b6, 0.f), fmaxf(acc[7] + b7, 0.f));
    out[(size_t)g * 16 + gl] = o;
}

// ---------------------------------------------------------------- launch
extern "C" void kernel_launch(void* const* d_in, const int* in_sizes, int n_in,
                              void* d_out, int out_size, void* d_ws, size_t ws_size,
                              hipStream_t stream)
{
    const float* xg  = (const float*)d_in[0];
    const float* xd  = (const float*)d_in[1];
    const float* Ws1 = (const float*)d_in[2];
    const float* Wd1 = (const float*)d_in[3];
    const float* as1 = (const float*)d_in[4];
    const float* ad1 = (const float*)d_in[5];
    const float* b1  = (const float*)d_in[6];
    const float* Ws2 = (const float*)d_in[7];
    const float* Wd2 = (const float*)d_in[8];
    const float* as2 = (const float*)d_in[9];
    const float* ad2 = (const float*)d_in[10];
    const float* b2  = (const float*)d_in[11];
    const float* Wg  = (const float*)d_in[12];
    const float* bg  = (const float*)d_in[13];
    const float* Wdh = (const float*)d_in[14];
    const float* bd  = (const float*)d_in[15];
    const int* gg_s = (const int*)d_in[16];
    const int* gg_d = (const int*)d_in[17];
    const int* gd_s = (const int*)d_in[18];
    const int* gd_d = (const int*)d_in[19];
    const int* dg_s = (const int*)d_in[20];
    const int* dg_d = (const int*)d_in[21];
    float* out = (float*)d_out;

    size_t p = 0;
    char* ws = (char*)d_ws;
    auto alloc_f = [&](size_t n) { p = (p + 255) & ~(size_t)255; float* r = (float*)(ws + p);  p += n * sizeof(float);  return r; };
    auto alloc_i = [&](size_t n) { p = (p + 255) & ~(size_t)255; int* r = (int*)(ws + p);      p += n * sizeof(int);    return r; };
    auto alloc_u = [&](size_t n) { p = (p + 255) & ~(size_t)255; ushort* r = (ushort*)(ws + p); p += n * sizeof(ushort); return r; };

    ushort* xgb  = alloc_u((size_t)NGENE * FDIM);
    ushort* xdb  = alloc_u((size_t)NDIS  * FDIM);
    ushort* hsu  = alloc_u((size_t)NSRC * HIDD);   // rows: gene t0=2n, t1=2n+1 | dis t2 = 2NG+d
    ushort* h1gb = alloc_u((size_t)NGENE * HIDD);
    ushort* h1db = alloc_u((size_t)NDIS  * HIDD);
    ushort* wt1  = alloc_u(3 * 128 * 128);
    ushort* wt2  = alloc_u(3 * 128 * 128);
    ushort* wtg  = alloc_u(64 * 128);
    ushort* wtd  = alloc_u(64 * 128);
    float* av   = alloc_f(12 * 128);
    float* esu  = alloc_f(NSRC);        // matches srcu indexing
    float* edu  = alloc_f(NSLOT);       // matches slot indexing
    int* counts   = alloc_i(NSLOT);
    int* rowptr   = alloc_i(NSLOT + 1);
    int* partials = alloc_i(256);
    int* colu     = alloc_i(ETOT);
    (void)ws_size; (void)in_sizes; (void)n_in; (void)out_size;

    const int SCAN_BLOCKS = (NSLOT + 2047) / 2048;   // 108

    ushort* hs_dis = hsu + (size_t)2 * NGENE * HIDD;
    float* es_dis = esu + 2 * NGENE;
    float* ed0 = edu;                    // gene dst of g2g
    float* ed1 = edu + NGENE;            // dis dst of g2d
    float* ed2 = edu + NGENE + NDIS;     // gene dst of d2g

    // ---- CSR build (shared by both layers); counts doubles as cursor
    hipMemsetAsync(counts, 0, (size_t)NSLOT * sizeof(int), stream);
    hist_edges<<<(ETOT + 255) / 256, 256, 0, stream>>>(gg_d, gd_d, dg_d, counts);
    scan_blocks<<<SCAN_BLOCKS, 256, 0, stream>>>(counts, rowptr, partials, NSLOT);
    scan_partials<<<1, 256, 0, stream>>>(partials, SCAN_BLOCKS);
    scan_add<<<(NSLOT + 255) / 256, 256, 0, stream>>>(rowptr, partials, NSLOT, counts);
    scatter_edges<<<(ETOT + 255) / 256, 256, 0, stream>>>(gg_s, gg_d, gd_s, gd_d, dg_s, dg_d,
                                                          counts, colu);

    // ---- bf16 conversions + attention vectors
    conv_f32_bf16<<<(NGENE * FDIM / 4 + 255) / 256, 256, 0, stream>>>(xg, xgb, NGENE * FDIM / 4);
    conv_f32_bf16<<<(NDIS  * FDIM / 4 + 255) / 256, 256, 0, stream>>>(xd, xdb, NDIS * FDIM / 4);
    conv_wt_all<<<448, 256, 0, stream>>>(Ws1, Ws2, Wg, Wdh, wt1, wt2, wtg, wtd);
    compute_av<<<1536, 64, 0, stream>>>(Ws1, Wd1, as1, ad1, Ws2, Wd2, as2, ad2, av);

    const int GB_G = (NGENE + 63) / 64, GB_D = (NDIS + 63) / 64;
    const int AB_G = (NGENE + 15) / 16, AB_D = (NDIS + 15) / 16;

    // ---- layer 1: fused dual projection + dots (gene), projection + dots (dis)
    gemm_mfma<256, 8, 4, true><<<GB_G, 512, 0, stream>>>(xgb, wt1, nullptr, hsu, NGENE,
        av, make_int4(0, 1, 3, 5), esu, ed0, ed2);
    gemm_mfma<128, 8, 2, true><<<GB_D, 512, 0, stream>>>(xdb, wt1 + 2 * 128 * 128, nullptr, hs_dis, NDIS,
        av, make_int4(2, 4, 0, 0), es_dis, ed1, nullptr);
    agg_seg<true><<<AB_G, 256, 0, stream>>>(rowptr, colu, esu, edu, (const uint4*)hsu,
        0, NGENE + NDIS, b1 + 0 * 128, b1 + 2 * 128, (uint4*)h1gb, NGENE);
    agg_seg<false><<<AB_D, 256, 0, stream>>>(rowptr, colu, esu, edu, (const uint4*)hsu,
        NGENE, 0, b1 + 1 * 128, nullptr, (uint4*)h1db, NDIS);

    // ---- layer 2
    gemm_mfma<256, 8, 4, true><<<GB_G, 512, 0, stream>>>(h1gb, wt2, nullptr, hsu, NGENE,
        av, make_int4(6, 7, 9, 11), esu, ed0, ed2);
    gemm_mfma<128, 8, 2, true><<<GB_D, 512, 0, stream>>>(h1db, wt2 + 2 * 128 * 128, nullptr, hs_dis, NDIS,
        av, make_int4(8, 10, 0, 0), es_dis, ed1, nullptr);
    agg_seg<true><<<AB_G, 256, 0, stream>>>(rowptr, colu, esu, edu, (const uint4*)hsu,
        0, NGENE + NDIS, b2 + 0 * 128, b2 + 2 * 128, (uint4*)h1gb, NGENE);
    agg_seg<false><<<AB_D, 256, 0, stream>>>(rowptr, colu, esu, edu, (const uint4*)hsu,
        NGENE, 0, b2 + 1 * 128, nullptr, (uint4*)h1db, NDIS);

    // ---- output heads (bf16 MFMA, fp32 out + bias, gene first)
    gemm_mfma<64, 4, 0, false><<<GB_G, 256, 0, stream>>>(h1gb, wtg, bg, out, NGENE,
        av, make_int4(0, 0, 0, 0), nullptr, nullptr, nullptr);
    gemm_mfma<64, 4, 0, false><<<GB_D, 256, 0, stream>>>(h1db, wtd, bd, out + (size_t)NGENE * OUTF, NDIS,
        av, make_int4(0, 0, 0, 0), nullptr, nullptr, nullptr);
}